// Round 12
// baseline (159.511 us; speedup 1.0000x reference)
//
#include <hip/hip_runtime.h>

#define B_ 4
#define N_ 4096
#define C_ 256
#define M_ 2048

typedef __attribute__((ext_vector_type(8))) short short8;
typedef __attribute__((ext_vector_type(4))) short short4v;
typedef __attribute__((ext_vector_type(4))) float f32x4;

union U16x8 { uint4 u4; unsigned short us[8]; short8 s8; };
union U16x4 { uint2 u2; unsigned short us[4]; short4v s4; };

__device__ __forceinline__ float bf2f(unsigned short h) {
    unsigned int u = ((unsigned int)h) << 16;
    return __builtin_bit_cast(float, u);
}
__device__ __forceinline__ unsigned short f2bf(float f) {
    unsigned int u = __builtin_bit_cast(unsigned int, f);
    u += 0x7FFFu + ((u >> 16) & 1u);
    return (unsigned short)(u >> 16);
}

// 16x16x16 bf16 MFMA: builtin if available, else raw encoding via inline asm.
__device__ __forceinline__ f32x4 mfma16x16(short4v a, short4v b, f32x4 c) {
#if __has_builtin(__builtin_amdgcn_mfma_f32_16x16x16bf16_1k)
    return __builtin_amdgcn_mfma_f32_16x16x16bf16_1k(a, b, c, 0, 0, 0);
#else
    asm("v_mfma_f32_16x16x16_bf16 %0, %1, %2, %0" : "+v"(c) : "v"(a), "v"(b));
    return c;
#endif
}

// ---- Fused prepass: norms + casts into FRAGMENT-LINEAR layouts. ----
// grid (M/64, B), 1024 thr. Per batch (1 MB each):
//   gmc2[t][kk][key64][quad]  : 8 bf16 (16B) = ghat[key=t*64+key64][c=kk*32+quad*8 ..+8]
//       idx = t*16384 + kk*2048 + key64*32 + quad*8
//   gcm2[t][ct][khq][cr][quad]: 4 bf16 (8B)  = graw[c=ct*16+cr][key=t*64+khq*16+quad*4 ..+4]
//       idx = t*16384 + ct*1024 + khq*256 + cr*16 + quad*4
// k_main reads these as perfectly-coalesced global loads (wave = 1KB / 512B
// contiguous) -- no LDS staging, no barriers, no swizzles.
__global__ __launch_bounds__(1024) void k_prep(const float* __restrict__ g,
                                               unsigned short* __restrict__ gcm2,
                                               unsigned short* __restrict__ gmc2) {
    __shared__ float red[16][64];
    __shared__ float sInv[64];
    __shared__ unsigned short T[64 * 66];   // normalized [c][m] tile, odd-dword stride
    const int b = blockIdx.y, m0 = blockIdx.x * 64;
    const int tid = threadIdx.x;                // 0..1023
    const int ml = tid & 63, cq = tid >> 6;     // cq in [0,16)

    // phase 1: norms — each thread sums 16 c-rows
    const float* gb = g + (size_t)b * C_ * M_ + m0 + ml;
    float ss = 0.f;
#pragma unroll 4
    for (int i = 0; i < 16; ++i) {
        float v = gb[(size_t)(cq * 16 + i) * M_];
        ss += v * v;
    }
    red[cq][ml] = ss;
    __syncthreads();
    if (cq == 0) {
        float t = 0.f;
#pragma unroll
        for (int k = 0; k < 16; ++k) t += red[k][ml];
        sInv[ml] = 1.f / fmaxf(sqrtf(t), 1e-8f);
    }
    __syncthreads();

    unsigned short* gmc2b = gmc2 + (size_t)b * 524288 + (size_t)blockIdx.x * 16384;
    unsigned short* gcm2b = gcm2 + (size_t)b * 524288 + (size_t)blockIdx.x * 16384;

    // phase 2: casts, 4 c-tiles of 64
    for (int c0 = 0; c0 < C_; c0 += 64) {
        const float* gbase = g + ((size_t)b * C_ + c0) * M_ + m0;
        {
            int ci = tid >> 4, mq = (tid & 15) * 4;   // ci: c within tile; mq: key, %4==0
            float4 v = *(const float4*)(gbase + (size_t)ci * M_ + mq);
            uint2 pk;
            pk.x = (unsigned)f2bf(v.x) | ((unsigned)f2bf(v.y) << 16);
            pk.y = (unsigned)f2bf(v.z) | ((unsigned)f2bf(v.w) << 16);
            const int cg = c0 + ci;
            // gcm2: one (c, 4-key) chunk
            *(uint2*)(gcm2b + (cg >> 4) * 1024 + (mq >> 4) * 256 + (cg & 15) * 16 +
                      ((mq >> 2) & 3) * 4) = pk;
            T[ci * 66 + mq + 0] = f2bf(v.x * sInv[mq + 0]);
            T[ci * 66 + mq + 1] = f2bf(v.y * sInv[mq + 1]);
            T[ci * 66 + mq + 2] = f2bf(v.z * sInv[mq + 2]);
            T[ci * 66 + mq + 3] = f2bf(v.w * sInv[mq + 3]);
        }
        __syncthreads();
        if (tid < 512) {                        // 512 8-short chunks
            int mr = tid >> 3, cc8 = (tid & 7) * 8;   // mr: key; cc8: c, %8==0
            U16x8 t8;
#pragma unroll
            for (int k = 0; k < 8; ++k) t8.us[k] = T[(cc8 + k) * 66 + mr];
            const int cg = c0 + cc8;
            // gmc2: one (key, 8-c) chunk
            *(uint4*)(gmc2b + (cg >> 5) * 2048 + mr * 32 + ((cg >> 3) & 3) * 8) = t8.u4;
        }
        __syncthreads();   // T reused next tile
    }
}

// ---------------- Main fused kernel (v17) ----------------
// v13 compute structure (64 rows/block, 8 waves, key-split, P in regs) with the
// LDS STAGING DELETED: fragment reads go straight to L2 via the fragment-linear
// layouts (g-stream is 100% L2-resident: FETCH=20MB, 2MB/XCD working set with
// the batch swizzle). Removes per iter: 64KB LDS DMA-writes + 128KB LDS reads
// + 2 barriers + all bank conflicts (v13: 4.19M, 34-40% LDS-port time; v16
// proved LDS serialization is the bind). Waves now run barrier-free and the
// compiler can pipeline loads across iterations unimpeded.
// LDS is used only for the (post-loop) denominator publish + O reduction.
__global__ __launch_bounds__(512, 1) void k_main(
    const float* __restrict__ l,
    const unsigned short* __restrict__ gcm2,   // fragment-linear raw   (GEMM2 B)
    const unsigned short* __restrict__ gmc2,   // fragment-linear ghat  (GEMM1 A)
    float* __restrict__ out)
{
    __shared__ __align__(16) char sMem[66560];
    float (*sDen)[64] = (float (*)[64])(sMem + 65536);         // [4 kh][64 rows]

    const int tid = threadIdx.x;
    const int w = tid >> 6;
    const int lane = tid & 63;
    const int l15 = lane & 15;
    const int quad = lane >> 4;
    const int kh = w & 3;        // key-quarter
    const int rh = w >> 2;       // row-half

    // ---- batch-clustered XCD swizzle (bijective over 256 blocks) ----
    const int bid = blockIdx.x;
    const int xcd = bid & 7;
    const int b = xcd >> 1;                                   // 2 XCDs per batch
    const int row0 = (((bid >> 3) << 1) | (xcd & 1)) * 64;    // 64-row tile in [0,4096)

    const unsigned short* gmc2_b = gmc2 + (size_t)b * 524288;
    const unsigned short* gcm2_b = gcm2 + (size_t)b * 524288;

    // ---- Q: my 32 rows (row-half rh), row norm, normalize -> bf16 B-frags ----
    short8 qf[2][8];
#pragma unroll
    for (int rt = 0; rt < 2; ++rt) {
        const float* lrow = l + ((size_t)b * N_ + row0 + rh * 32 + rt * 16 + l15) * C_;
        U16x8 qt[8];
        float ss = 0.f;
#pragma unroll
        for (int kk = 0; kk < 8; ++kk) {
            float4 x0 = *(const float4*)(lrow + kk * 32 + quad * 8);
            float4 x1 = *(const float4*)(lrow + kk * 32 + quad * 8 + 4);
            ss += x0.x*x0.x + x0.y*x0.y + x0.z*x0.z + x0.w*x0.w;
            ss += x1.x*x1.x + x1.y*x1.y + x1.z*x1.z + x1.w*x1.w;
            qt[kk].us[0] = f2bf(x0.x); qt[kk].us[1] = f2bf(x0.y);
            qt[kk].us[2] = f2bf(x0.z); qt[kk].us[3] = f2bf(x0.w);
            qt[kk].us[4] = f2bf(x1.x); qt[kk].us[5] = f2bf(x1.y);
            qt[kk].us[6] = f2bf(x1.z); qt[kk].us[7] = f2bf(x1.w);
        }
        ss += __shfl_xor(ss, 16);
        ss += __shfl_xor(ss, 32);
        const float invl = 1.0f / fmaxf(sqrtf(ss), 1e-8f);
#pragma unroll
        for (int kk = 0; kk < 8; ++kk) {
            U16x8 t;
#pragma unroll
            for (int j = 0; j < 8; ++j) t.us[j] = f2bf(bf2f(qt[kk].us[j]) * invl);
            qf[rt][kk] = t.s8;
        }
    }

    f32x4 zero = {0.f, 0.f, 0.f, 0.f};
    f32x4 o[2][16];    // per-wave PARTIAL O (its 16 keys): [row-tile][c-tile 16c]
#pragma unroll
    for (int i = 0; i < 2; ++i)
#pragma unroll
        for (int j = 0; j < 16; ++j) o[i][j] = zero;
    float dl0 = 0.f, dl1 = 0.f;

    // fragment-linear per-lane bases (see k_prep header comment)
    const unsigned short* gAbase = gmc2_b + (kh * 16 + l15) * 32 + quad * 8;   // + mt*16384 + kk*2048
    const unsigned short* gBbase = gcm2_b + kh * 256 + l15 * 16 + quad * 4;    // + mt*16384 + ct*1024

    // ---- barrier-free main loop over 32 key-tiles ----
    for (int mt = 0; mt < 32; ++mt) {
        const unsigned short* gA = gAbase + (size_t)mt * 16384;
        const unsigned short* gB = gBbase + (size_t)mt * 16384;

        // GEMM1 (swapped): S^T[16 keys][16 rows] per row-tile, K=256
        f32x4 sa0 = zero, sa1 = zero;
#pragma unroll
        for (int kk = 0; kk < 8; ++kk) {
            short8 ag = *(const short8*)&gA[kk * 2048];
            sa0 = __builtin_amdgcn_mfma_f32_16x16x32_bf16(ag, qf[0][kk], sa0, 0, 0, 0);
            sa1 = __builtin_amdgcn_mfma_f32_16x16x32_bf16(ag, qf[1][kk], sa1, 0, 0, 0);
        }
        // p = exp(cos/tau); lane holds (q-row = l15, key = quad*4+r) -> already
        // the 16x16x16 A-frag layout. Accumulate denominator partials.
        U16x4 pk0, pk1;
#pragma unroll
        for (int r = 0; r < 4; ++r) {
            float p0 = exp2f(sa0[r] * 3.6067376022224085f);
            float p1 = exp2f(sa1[r] * 3.6067376022224085f);
            dl0 += p0; dl1 += p1;
            pk0.us[r] = f2bf(p0);
            pk1.us[r] = f2bf(p1);
        }

        // GEMM2 key-split: O_partial[32 rows][256 c] += P[32][16 keys] * V[16][256]
#pragma unroll
        for (int ct = 0; ct < 16; ++ct) {
            short4v bb = *(const short4v*)&gB[ct * 1024];
            o[0][ct] = mfma16x16(pk0.s4, bb, o[0][ct]);
            o[1][ct] = mfma16x16(pk1.s4, bb, o[1][ct]);
        }
    }

    // ---- denominators: quad-reduce, publish per key-quarter per row ----
    {
        float d0 = dl0;
        d0 += __shfl_xor(d0, 16);
        d0 += __shfl_xor(d0, 32);
        float d1 = dl1;
        d1 += __shfl_xor(d1, 16);
        d1 += __shfl_xor(d1, 32);
        if (quad == 0) {
            sDen[kh][rh * 32 + l15] = d0;
            sDen[kh][rh * 32 + 16 + l15] = d1;
        }
    }

    // ---- O reduction: 4 static rounds (rh x rt) through 64 KB LDS dump ----
    // slot(kh', j, quad, l15) = kh'*1024 + j*64 + quad*16 + l15  (f32x4 units)
    // All indices static (rule #20). red4 covers sMem[0,65536); sDen at 65536.
    f32x4* red4 = (f32x4*)sMem;
    const int wslot = kh * 1024 + quad * 16 + l15;       // + j*64
    const int rslot = (4 * kh) * 64 + quad * 16 + l15;   // + jj*64 + kh'*1024
    f32x4 oacc0[4], oacc1[4];

#define RED_ROUND(RH, OSRC, ODST)                                              \
    __syncthreads();                                                           \
    if (rh == (RH)) {                                                          \
        _Pragma("unroll")                                                      \
        for (int j = 0; j < 16; ++j) red4[wslot + j * 64] = OSRC[j];           \
    }                                                                          \
    __syncthreads();                                                           \
    if (rh == (RH)) {                                                          \
        _Pragma("unroll")                                                      \
        for (int jj = 0; jj < 4; ++jj) {                                       \
            const int base = rslot + jj * 64;                                  \
            ODST[jj] = red4[base] + red4[base + 1024] +                        \
                       red4[base + 2048] + red4[base + 3072];                  \
        }                                                                      \
    }

    RED_ROUND(0, o[0], oacc0)
    RED_ROUND(0, o[1], oacc1)
    RED_ROUND(1, o[0], oacc0)
    RED_ROUND(1, o[1], oacc1)
#undef RED_ROUND

    // ---- epilogue: wave (kh, rh) owns rows [32rh,32rh+32), c [64kh, 64kh+64) ----
    const float* lb = l + ((size_t)b * N_ + row0 + rh * 32) * C_;
    float* ob = out + ((size_t)b * N_ + row0 + rh * 32) * C_;
#pragma unroll
    for (int r = 0; r < 4; ++r) {
        {   // row-tile 0
            const int row = quad * 4 + r;
            const int grow = rh * 32 + row;
            const float inv = 1.f / (sDen[0][grow] + sDen[1][grow] + sDen[2][grow] + sDen[3][grow]);
            const size_t rb = (size_t)row * C_;
#pragma unroll
            for (int jj = 0; jj < 4; ++jj) {
                const int c = kh * 64 + jj * 16 + l15;
                ob[rb + c] = lb[rb + c] + oacc0[jj][r] * inv;
            }
        }
        {   // row-tile 1
            const int row = 16 + quad * 4 + r;
            const int grow = rh * 32 + row;
            const float inv = 1.f / (sDen[0][grow] + sDen[1][grow] + sDen[2][grow] + sDen[3][grow]);
            const size_t rb = (size_t)row * C_;
#pragma unroll
            for (int jj = 0; jj < 4; ++jj) {
                const int c = kh * 64 + jj * 16 + l15;
                ob[rb + c] = lb[rb + c] + oacc1[jj][r] * inv;
            }
        }
    }
}

extern "C" void kernel_launch(void* const* d_in, const int* in_sizes, int n_in,
                              void* d_out, int out_size, void* d_ws, size_t ws_size,
                              hipStream_t stream) {
    (void)in_sizes; (void)n_in; (void)out_size; (void)ws_size;
    const float* l = (const float*)d_in[0];
    const float* g = (const float*)d_in[1];
    float* outp = (float*)d_out;

    char* ws = (char*)d_ws;
    unsigned short* gmc2 = (unsigned short*)ws;                                  // 4 MB (fragment-linear ghat)
    unsigned short* gcm2 = (unsigned short*)(ws + (size_t)B_ * M_ * C_ * 2);     // 4 MB (fragment-linear raw)

    k_prep<<<dim3(M_ / 64, B_), 1024, 0, stream>>>(g, gcm2, gmc2);
    k_main<<<dim3(N_ / 64 * B_), 512, 0, stream>>>(l, gcm2, gmc2, outp);
}